// Round 1
// 2580.999 us; speedup vs baseline: 1.1366x; 1.1366x over previous
//
#include <hip/hip_runtime.h>
#include <hip/hip_bf16.h>
#include <stdint.h>

typedef unsigned short u16;
typedef __attribute__((ext_vector_type(4))) float floatx4;
typedef __attribute__((ext_vector_type(8))) short bf16x8;
typedef __attribute__((ext_vector_type(8))) unsigned short u16x8;
typedef const __attribute__((address_space(1))) void gvoid;
typedef __attribute__((address_space(3))) void lvoid;

static constexpr int Mdim = 4096;   // B*S = 4*1024
static constexpr int Hdim = 5120;
static constexpr int Idim = 12288;
static constexpr float QINV = 1.0f / 127.0f;

static __device__ __forceinline__ u16 f2b(float f) {
    __hip_bfloat16 h = __float2bfloat16(f);
    return *(u16*)&h;
}

// ---- int32 -> bf16 weight conversion (values in [-127,127] are exact in bf16)
__global__ void conv_i32_to_bf16(const int* __restrict__ in, u16* __restrict__ out) {
    int idx = (blockIdx.x * 256 + threadIdx.x) * 8;
    int4 v0 = *(const int4*)(in + idx);
    int4 v1 = *(const int4*)(in + idx + 4);
    u16x8 o;
    o[0] = f2b((float)v0.x); o[1] = f2b((float)v0.y);
    o[2] = f2b((float)v0.z); o[3] = f2b((float)v0.w);
    o[4] = f2b((float)v1.x); o[5] = f2b((float)v1.y);
    o[6] = f2b((float)v1.z); o[7] = f2b((float)v1.w);
    *(u16x8*)(out + idx) = o;
}

// ---- f32 -> bf16 activation conversion
__global__ void conv_f32_to_bf16(const float* __restrict__ in, u16* __restrict__ out) {
    int idx = (blockIdx.x * 256 + threadIdx.x) * 8;
    float4 v0 = *(const float4*)(in + idx);
    float4 v1 = *(const float4*)(in + idx + 4);
    u16x8 o;
    o[0] = f2b(v0.x); o[1] = f2b(v0.y); o[2] = f2b(v0.z); o[3] = f2b(v0.w);
    o[4] = f2b(v1.x); o[5] = f2b(v1.y); o[6] = f2b(v1.z); o[7] = f2b(v1.w);
    *(u16x8*)(out + idx) = o;
}

// ============================================================================
// 256x256-tile bf16 GEMM, C[m][n] = sum_k A[m,k]*W[n,k], fused epilogues.
// T3+T4 deep pipeline: BK=32, 4 LDS buffers (4 x 32KiB = 128 KiB), stages for
// tile t+3 issued while computing tile t; vmcnt(8) ONCE per K-tile boundary
// (never 0 in the main loop) -> 2 tiles' loads stay in flight across barriers.
// Race-free: buf[(t+3)&3]'s previous reader (tile t-1) finished at the barrier
// that precedes the stage issue; no buffer is read and written concurrently.
// LDS swizzle: 16B unit u of row r holds global chunk u ^ ((r>>1)&3); applied
// on the global SOURCE of global_load_lds (dest stays linear per m104/m173)
// and identically on the ds_read address. Spreads the 16 lanes of each
// lg-group across all 8 bank groups exactly 2x (2-way = free per m136).
// Waves: 8 (2M x 4N), wave tile 128x64, acc[8][4] floatx4.
// MODE 0: GateBuf = bf16(silu(acc*s))        (gate projection)
// MODE 1: GateBuf = bf16(GateBuf * acc*s)    (up projection, in-place gate*up)
// MODE 2: OutF    = acc*s                    (down projection, fp32 out)
// ============================================================================
template<int MODE>
__global__ __launch_bounds__(512, 2)
void gemm256(const u16* __restrict__ A, const u16* __restrict__ Bw,
             const float* __restrict__ scale, u16* __restrict__ GateBuf,
             float* __restrict__ OutF, int N, int K, int nbx)
{
    __shared__ u16 As[4 * 8192];   // 4 buffers x 256 rows x 32 elems (64 KiB)
    __shared__ u16 Bs[4 * 8192];   // 64 KiB

    const int tid  = threadIdx.x;
    const int lane = tid & 63;
    const int wave = tid >> 6;
    const int wm = (wave >> 2) * 128;   // wave row offset in tile (2 M-waves)
    const int wn = (wave & 3) * 64;     // wave col offset in tile (4 N-waves)
    const int lm = lane & 15;
    const int lg = lane >> 4;           // which 8-elem K chunk

    // T1: bijective XCD swizzle (nwg % 8 == 0 for all launches here).
    // Consecutive swz within an XCD share col0 -> B-panel L2 reuse.
    const int nwg = gridDim.x;
    const int bid = blockIdx.x;
    const int swz = (bid & 7) * (nwg >> 3) + (bid >> 3);
    const int row0 = (swz % nbx) * 256;
    const int col0 = (swz / nbx) * 256;

    const u16* Ablk = A  + (size_t)row0 * K;
    const u16* Bblk = Bw + (size_t)col0 * K;

    // staging constants: thread owns 16B unit w=tid (row rs, unit u) and w=tid+512
    // (row rs+128, same u, same swizzle since (r+128)>>1 keeps low bits).
    const int rs  = tid >> 2;
    const int csw = ((tid & 3) ^ ((rs >> 1) & 3)) << 3;   // swizzled elem offset
    const u16* aS = Ablk + (size_t)rs * K + csw;
    const u16* bS = Bblk + (size_t)rs * K + csw;
    const size_t rK128 = (size_t)128 * K;
    u16* aD = As + tid * 8;
    u16* bD = Bs + tid * 8;

    // ds_read swizzle: row = 16*frag + lm, so x(row) = (lm>>1)&3
    const int koff = (lg ^ ((lm >> 1) & 3)) << 3;

    floatx4 acc[8][4];
    #pragma unroll
    for (int i = 0; i < 8; i++)
        #pragma unroll
        for (int j = 0; j < 4; j++)
            acc[i][j] = (floatx4){0.f, 0.f, 0.f, 0.f};

    const int nt = K >> 5;   // K-tiles of 32

#define STAGE_A(t) do { \
    const u16* s_ = aS + (size_t)(t) * 32; \
    u16* d_ = aD + ((t) & 3) * 8192; \
    __builtin_amdgcn_global_load_lds((gvoid*)s_, (lvoid*)d_, 16, 0, 0); \
    __builtin_amdgcn_global_load_lds((gvoid*)(s_ + rK128), (lvoid*)(d_ + 4096), 16, 0, 0); \
} while (0)

#define STAGE_B(t) do { \
    const u16* s_ = bS + (size_t)(t) * 32; \
    u16* d_ = bD + ((t) & 3) * 8192; \
    __builtin_amdgcn_global_load_lds((gvoid*)s_, (lvoid*)d_, 16, 0, 0); \
    __builtin_amdgcn_global_load_lds((gvoid*)(s_ + rK128), (lvoid*)(d_ + 4096), 16, 0, 0); \
} while (0)

// one phase: ds-read 8 frags || issue 1 half-stage -> barrier -> MFMA cluster
// (setprio-wrapped, T5) -> [vmcnt at tile boundary] -> barrier
#define PHASE(qr, STG, WAITV) do { \
    bf16x8 af[4], bf[4]; \
    const u16* Ab_ = As + bufo; \
    const u16* Bb_ = Bs + bufo; \
    _Pragma("unroll") \
    for (int i = 0; i < 4; i++) \
        af[i] = *(const bf16x8*)(Ab_ + (wm + ((qr) * 4 + i) * 16 + lm) * 32 + koff); \
    _Pragma("unroll") \
    for (int j = 0; j < 4; j++) \
        bf[j] = *(const bf16x8*)(Bb_ + (wn + j * 16 + lm) * 32 + koff); \
    STG; \
    asm volatile("" ::: "memory"); \
    __builtin_amdgcn_s_barrier(); \
    __builtin_amdgcn_s_setprio(1); \
    _Pragma("unroll") \
    for (int i = 0; i < 4; i++) \
        _Pragma("unroll") \
        for (int j = 0; j < 4; j++) \
            acc[(qr) * 4 + i][j] = __builtin_amdgcn_mfma_f32_16x16x32_bf16( \
                af[i], bf[j], acc[(qr) * 4 + i][j], 0, 0, 0); \
    __builtin_amdgcn_s_setprio(0); \
    WAITV; \
    asm volatile("" ::: "memory"); \
    __builtin_amdgcn_s_barrier(); \
} while (0)

    // prologue: stage tiles 0,1,2 (12 loads); tile 0 landed when vmcnt<=8
    STAGE_A(0); STAGE_B(0);
    STAGE_A(1); STAGE_B(1);
    STAGE_A(2); STAGE_B(2);
    asm volatile("s_waitcnt vmcnt(8)" ::: "memory");
    __builtin_amdgcn_s_barrier();

    // main loop: compute tile t, stage tile t+3. At the boundary the 8 newest
    // loads (tiles t+2,t+3) may be in flight; tile t+1 is guaranteed landed.
    int t = 0;
    for (; t < nt - 3; ++t) {
        const int bufo = (t & 3) * 8192;
        PHASE(0, STAGE_A(t + 3), (void)0);
        PHASE(1, STAGE_B(t + 3), asm volatile("s_waitcnt vmcnt(8)" ::: "memory"));
    }
    // epilogue tiles: drain 8 -> 4 -> 0
    {
        const int bufo = (t & 3) * 8192;
        PHASE(0, (void)0, (void)0);
        PHASE(1, (void)0, asm volatile("s_waitcnt vmcnt(4)" ::: "memory"));
        ++t;
    }
    {
        const int bufo = (t & 3) * 8192;
        PHASE(0, (void)0, (void)0);
        PHASE(1, (void)0, asm volatile("s_waitcnt vmcnt(0)" ::: "memory"));
        ++t;
    }
    {
        const int bufo = (t & 3) * 8192;
        PHASE(0, (void)0, (void)0);
        PHASE(1, (void)0, (void)0);
    }
#undef PHASE
#undef STAGE_A
#undef STAGE_B

    // epilogue: C/D layout col=lane&15, row=(lane>>4)*4+reg   [m89-verified]
    const int ln = lane & 15;
    const int rq = (lane >> 4) * 4;
    #pragma unroll
    for (int j = 0; j < 4; j++) {
        const int col = col0 + wn + j * 16 + ln;
        const float s = scale[col] * QINV;
        #pragma unroll
        for (int i = 0; i < 8; i++) {
            const int rowb = row0 + wm + i * 16 + rq;
            #pragma unroll
            for (int r = 0; r < 4; r++) {
                const size_t idx = (size_t)(rowb + r) * N + col;
                float v = acc[i][j][r] * s;
                if (MODE == 0) {
                    float g = v / (1.0f + __expf(-v));   // silu
                    GateBuf[idx] = f2b(g);
                } else if (MODE == 1) {
                    u16 gu = GateBuf[idx];
                    float g = __bfloat162float(*(__hip_bfloat16*)&gu);
                    GateBuf[idx] = f2b(g * v);
                } else {
                    OutF[idx] = v;
                }
            }
        }
    }
}

extern "C" void kernel_launch(void* const* d_in, const int* in_sizes, int n_in,
                              void* d_out, int out_size, void* d_ws, size_t ws_size,
                              hipStream_t stream)
{
    const float* x  = (const float*)d_in[0];
    const int*   wg = (const int*)d_in[1];
    const float* sg = (const float*)d_in[2];
    const int*   wu = (const int*)d_in[3];
    const float* su = (const float*)d_in[4];
    const int*   wd = (const int*)d_in[5];
    const float* sd = (const float*)d_in[6];
    float* out = (float*)d_out;

    char* ws = (char*)d_ws;
    u16* xb   = (u16*)ws;                                        // 4096*5120 bf16   (42 MB)
    u16* wb   = (u16*)(ws + 41943040);                           // 62914560 bf16    (126 MB, reused 3x)
    u16* gate = (u16*)(ws + 41943040 + 125829120);               // 4096*12288 bf16  (100 MB, gate then h)

    // x: 20971520 elems / 2048 per block
    conv_f32_to_bf16<<<10240, 256, 0, stream>>>(x, xb);

    // gate = silu((x @ Wg^T) * sg/127)
    conv_i32_to_bf16<<<30720, 256, 0, stream>>>(wg, wb);
    gemm256<0><<<(Mdim / 256) * (Idim / 256), 512, 0, stream>>>(
        xb, wb, sg, gate, nullptr, Idim, Hdim, Mdim / 256);

    // h = gate * ((x @ Wu^T) * su/127)   (in-place over gate)
    conv_i32_to_bf16<<<30720, 256, 0, stream>>>(wu, wb);
    gemm256<1><<<(Mdim / 256) * (Idim / 256), 512, 0, stream>>>(
        xb, wb, su, gate, nullptr, Idim, Hdim, Mdim / 256);

    // out = (h @ Wd^T) * sd/127
    conv_i32_to_bf16<<<30720, 256, 0, stream>>>(wd, wb);
    gemm256<2><<<(Mdim / 256) * (Hdim / 256), 512, 0, stream>>>(
        gate, wb, sd, nullptr, out, Hdim, Idim, Mdim / 256);
}